// Round 6
// baseline (262.786 us; speedup 1.0000x reference)
//
#include <hip/hip_runtime.h>
#include <math.h>

// NetVLAD on MI355X via bf16 hi/lo-split MFMA, per-pass LDS slab layouts.
// N=128 images, C=256 channels, K=64 clusters, P=1024 pixels.
// Block = (image, eighth): 128 pixels, 256 threads = 4 waves, 1024 blocks,
// 3 blocks/CU (LDS 53KB). Single-buffer T14 staging (load->regs early,
// write after barrier).
// Pass 1 (GEMM1, contraction over c): slab layout [p][c] stride 36 ->
//   B-frags are contiguous ds_read_b128. logits[k][p] = W @ x_raw.
// Pass 2 (GEMM2 TRANSPOSED, contraction over p): slab layout [c][p] stride 132
//   aggT[c][k] = sum_p x[c][p]*a'[k][p]; A=x frags, B=a' frags both contiguous.
// MFMA 16x16x32 bf16: A row=l15,k=8*lg4+j; B col=l15,same k;
//                     C col=l15,row=4*lg4+reg  (verified R2-R5)

#define EPSF 1e-12f
#define XS1_LD 36      // u32 stride, pass-1 slab [128 p][32 c]
#define XS2_LD 132     // u32 stride, pass-2 slab [32 c][128 p]
#define BUF_LD 132     // u32/f32 stride, logits/a buffer [64 k][128 p + 4 pad]

typedef __attribute__((ext_vector_type(8))) __bf16 bf16x8;
typedef __attribute__((ext_vector_type(4))) float f32x4;
typedef __attribute__((ext_vector_type(4))) unsigned int u32x4;

#define MFMA(a, b, c) __builtin_amdgcn_mfma_f32_16x16x32_bf16((a), (b), (c), 0, 0, 0)

__device__ __forceinline__ bf16x8 as_bf(u32x4 v) { return __builtin_bit_cast(bf16x8, v); }

// f32 -> packed (hi_bf16 << 16) | lo_bf16  (truncation split, err ~2^-16|x|)
__device__ __forceinline__ unsigned packsplit(float x) {
    const unsigned u  = __float_as_uint(x);
    const unsigned hi = u & 0xFFFF0000u;
    const float lof   = x - __uint_as_float(hi);
    return hi | (__float_as_uint(lof) >> 16);
}

// 8 packed u32 (two aligned quads) -> (hi,lo) MFMA operand pair
__device__ __forceinline__ void unpack2q(const u32x4 q0, const u32x4 q1,
                                         u32x4& hi, u32x4& lo) {
    hi[0] = __builtin_amdgcn_perm(q0[1], q0[0], 0x07060302u);
    lo[0] = __builtin_amdgcn_perm(q0[1], q0[0], 0x05040100u);
    hi[1] = __builtin_amdgcn_perm(q0[3], q0[2], 0x07060302u);
    lo[1] = __builtin_amdgcn_perm(q0[3], q0[2], 0x05040100u);
    hi[2] = __builtin_amdgcn_perm(q1[1], q1[0], 0x07060302u);
    lo[2] = __builtin_amdgcn_perm(q1[1], q1[0], 0x05040100u);
    hi[3] = __builtin_amdgcn_perm(q1[3], q1[2], 0x07060302u);
    lo[3] = __builtin_amdgcn_perm(q1[3], q1[2], 0x05040100u);
}

__device__ __forceinline__ void split8v(const float* xv, u32x4& hi, u32x4& lo) {
    unsigned uh[8], ul[8];
    #pragma unroll
    for (int j = 0; j < 8; ++j) {
        const unsigned u = __float_as_uint(xv[j]);
        uh[j] = u;
        const float hif = __uint_as_float(u & 0xFFFF0000u);
        ul[j] = __float_as_uint(xv[j] - hif);
    }
    #pragma unroll
    for (int w2 = 0; w2 < 4; ++w2) {
        hi[w2] = (uh[2*w2+1] & 0xFFFF0000u) | (uh[2*w2] >> 16);
        lo[w2] = (ul[2*w2+1] & 0xFFFF0000u) | (ul[2*w2] >> 16);
    }
}

__global__ __launch_bounds__(256, 3) void netvlad_mfma(
    const float* __restrict__ x, const float* __restrict__ wmat,
    const float* __restrict__ bias, float* __restrict__ out,
    float* __restrict__ asum_g) {

    __shared__ __align__(16) unsigned xs[128 * XS1_LD];    // pass1/pass2 slab union
    __shared__ __align__(16) unsigned buf[64 * BUF_LD];    // logits f32 -> packed a; pad = sspart
    __shared__ __align__(16) float rn_lds[128];
    __shared__ float bias_lds[64];
    float* buf_f = (float*)buf;

    const int t = threadIdx.x;
    const int w = t >> 6, l = t & 63;
    const int l15 = l & 15, lg4 = l >> 4;
    const int n = blockIdx.x >> 3, e = blockIdx.x & 7;
    const size_t ximg = (size_t)n * 256 * 1024;
    const int p0 = e * 128;
    const int k0 = w * 16;                 // wave's cluster tile (M in P1, N in P2)
    const int cs = lg4 * 8;                // contraction slice base within K-step

    if (t < 64) bias_lds[t] = bias[t];

    // ---- W fragments (GEMM1 A), resident through pass 1: 64 VGPRs
    u32x4 whi[8], wlo[8];
    {
        const float* wr = wmat + (k0 + l15) * 256 + cs;
        #pragma unroll
        for (int s = 0; s < 8; ++s) {
            float xv[8];
            const float4 f0 = *(const float4*)(wr + s * 32);
            const float4 f1 = *(const float4*)(wr + s * 32 + 4);
            xv[0]=f0.x; xv[1]=f0.y; xv[2]=f0.z; xv[3]=f0.w;
            xv[4]=f1.x; xv[5]=f1.y; xv[6]=f1.z; xv[7]=f1.w;
            split8v(xv, whi[s], wlo[s]);
        }
    }

    // ---- pass-1 staging: thread owns (pixel pp, channel half), 16 ch/slab
    const int pp = t & 127, half = t >> 7;
    const float* xg1 = x + ximg + (size_t)(half * 16) * 1024 + p0 + pp;
    unsigned* xw1 = xs + pp * XS1_LD + half * 16;
    float g[16];
    float ssacc = 0.f;

    #define P1_LOAD(s_) { _Pragma("unroll")                                   \
        for (int i = 0; i < 16; ++i)                                          \
            g[i] = xg1[(size_t)((s_) * 32 + i) * 1024]; }
    #define P1_WRITE() { _Pragma("unroll")                                    \
        for (int q = 0; q < 4; ++q) {                                         \
            u32x4 v;                                                          \
            _Pragma("unroll")                                                 \
            for (int j = 0; j < 4; ++j) {                                     \
                const float gv = g[q * 4 + j];                                \
                ssacc = fmaf(gv, gv, ssacc);                                  \
                v[j] = packsplit(gv);                                         \
            }                                                                 \
            *(u32x4*)(xw1 + q * 4) = v; } }

    // ================= PASS 1: logits + ss =================
    f32x4 acc1[8];
    #pragma unroll
    for (int i = 0; i < 8; ++i) acc1[i] = f32x4{0.f, 0.f, 0.f, 0.f};

    P1_LOAD(0);
    P1_WRITE();
    __syncthreads();
    #pragma unroll
    for (int s = 0; s < 8; ++s) {
        if (s < 7) P1_LOAD(s + 1);
        #pragma unroll
        for (int nt = 0; nt < 8; ++nt) {
            const unsigned* rp = xs + (nt * 16 + l15) * XS1_LD + cs;
            const u32x4 q0 = *(const u32x4*)rp;
            const u32x4 q1 = *(const u32x4*)(rp + 4);
            u32x4 bhi, blo; unpack2q(q0, q1, bhi, blo);
            acc1[nt] = MFMA(as_bf(whi[s]), as_bf(bhi), acc1[nt]);
            acc1[nt] = MFMA(as_bf(whi[s]), as_bf(blo), acc1[nt]);
            acc1[nt] = MFMA(as_bf(wlo[s]), as_bf(bhi), acc1[nt]);
        }
        __syncthreads();                       // everyone done reading slab s
        if (s < 7) { P1_WRITE(); __syncthreads(); }
    }

    // write raw logits + ss partials to buf (pad cols 128..131 hold sspart)
    #pragma unroll
    for (int nt = 0; nt < 8; ++nt) {
        #pragma unroll
        for (int r = 0; r < 4; ++r)
            buf_f[(k0 + lg4 * 4 + r) * BUF_LD + nt * 16 + l15] = acc1[nt][r];
    }
    buf_f[(t >> 2) * BUF_LD + 128 + (t & 3)] = ssacc;

    // ---- pass-2 staging ids; issue slab-0 loads early (hide under softmax)
    const int c2 = t >> 3, pq = (t & 7) * 4;
    const float* xg2 = x + ximg + (size_t)c2 * 1024 + p0 + pq;
    unsigned* xw2 = xs + c2 * XS2_LD + pq;
    float4 g2[4];
    #define P2_LOAD(s_) { _Pragma("unroll")                                   \
        for (int i = 0; i < 4; ++i)                                           \
            g2[i] = *(const float4*)(xg2 + (size_t)(s_) * 32768 + 32 * i); }
    #define P2_WRITE() { _Pragma("unroll")                                    \
        for (int i = 0; i < 4; ++i) {                                         \
            u32x4 v;                                                          \
            v[0] = packsplit(g2[i].x); v[1] = packsplit(g2[i].y);             \
            v[2] = packsplit(g2[i].z); v[3] = packsplit(g2[i].w);             \
            *(u32x4*)(xw2 + 32 * i) = v; } }
    P2_LOAD(0);
    __syncthreads();

    // ---- softmax: one pixel per thread (t<128); rn folded here
    if (t < 128) {
        const float ssv = buf_f[(t >> 2) * BUF_LD + 128 + (t & 3)]
                        + buf_f[((t >> 2) + 32) * BUF_LD + 128 + (t & 3)];
        const float rn = 1.f / fmaxf(sqrtf(ssv), EPSF);
        rn_lds[t] = rn;
        float a[64];
        #pragma unroll
        for (int k = 0; k < 64; ++k)
            a[k] = fmaf(buf_f[k * BUF_LD + t], rn, bias_lds[k]);
        float mx = -3.402823466e38f;
        #pragma unroll
        for (int k = 0; k < 64; ++k) mx = fmaxf(mx, a[k]);
        float den = 0.f;
        #pragma unroll
        for (int k = 0; k < 64; ++k) { a[k] = __expf(a[k] - mx); den += a[k]; }
        const float inv = 1.f / den;
        #pragma unroll
        for (int k = 0; k < 64; ++k)
            buf[k * BUF_LD + t] = packsplit(a[k] * inv);   // raw a, packed split
    }
    __syncthreads();

    // stage pass-2 slab 0 (xs free: pass 1 done reading)
    P2_WRITE();

    // ---- B-frags for pass 2: raw a (asum) + a*rn resplit; registers for all 8 slabs
    u32x4 aphi[4], aplo[4];
    f32x4 asum_acc = f32x4{0.f, 0.f, 0.f, 0.f};
    const u32x4 ONES = {0x3F803F80u, 0x3F803F80u, 0x3F803F80u, 0x3F803F80u};
    #pragma unroll
    for (int ks = 0; ks < 4; ++ks) {
        const unsigned* ap = buf + (k0 + l15) * BUF_LD + ks * 32 + cs;
        const u32x4 pa = *(const u32x4*)ap;
        const u32x4 pb = *(const u32x4*)(ap + 4);
        u32x4 ahi, alo; unpack2q(pa, pb, ahi, alo);
        asum_acc = MFMA(as_bf(ahi), as_bf(ONES), asum_acc);
        asum_acc = MFMA(as_bf(alo), as_bf(ONES), asum_acc);
        // a' = a*rn, resplit once; reused by all 16 c-tiles
        const float* rp = rn_lds + ks * 32 + cs;
        float av[8];
        #pragma unroll
        for (int j = 0; j < 8; ++j) {
            const float af = __uint_as_float(pa[0] & 0u); // placeholder removed below
            (void)af;
        }
        {
            const unsigned paw[8] = {pa[0],pa[1],pa[2],pa[3],pb[0],pb[1],pb[2],pb[3]};
            #pragma unroll
            for (int j = 0; j < 8; ++j) {
                const float afv = __uint_as_float(paw[j] & 0xFFFF0000u)
                                + __uint_as_float(paw[j] << 16);
                av[j] = afv * rp[j];
            }
        }
        split8v(av, aphi[ks], aplo[ks]);
    }
    __syncthreads();                           // slab 0 visible to all

    // ================= PASS 2 (transposed): aggT[c][k] =================
    float* op = out + (size_t)n * 16384;
    #pragma unroll
    for (int s2 = 0; s2 < 8; ++s2) {
        if (s2 < 7) P2_LOAD(s2 + 1);
        #pragma unroll
        for (int ct = 0; ct < 2; ++ct) {
            f32x4 a2 = f32x4{0.f, 0.f, 0.f, 0.f};
            #pragma unroll
            for (int ks = 0; ks < 4; ++ks) {
                const unsigned* rp = xs + (ct * 16 + l15) * XS2_LD + ks * 32 + cs;
                const u32x4 q0 = *(const u32x4*)rp;
                const u32x4 q1 = *(const u32x4*)(rp + 4);
                u32x4 xhi, xlo; unpack2q(q0, q1, xhi, xlo);
                a2 = MFMA(as_bf(xhi), as_bf(aphi[ks]), a2);
                a2 = MFMA(as_bf(xhi), as_bf(aplo[ks]), a2);
                a2 = MFMA(as_bf(xlo), as_bf(aphi[ks]), a2);
            }
            // C: col=l15 -> cluster k0+l15, row=4*lg4+r -> channel
            #pragma unroll
            for (int r = 0; r < 4; ++r)
                atomicAdd(&op[(k0 + l15) * 256 + s2 * 32 + ct * 16 + lg4 * 4 + r],
                          a2[r]);
        }
        __syncthreads();                       // done reading slab s2
        if (s2 < 7) { P2_WRITE(); __syncthreads(); }
    }
    if (l15 == 0) {
        #pragma unroll
        for (int r = 0; r < 4; ++r)
            atomicAdd(&asum_g[n * 64 + k0 + lg4 * 4 + r], asum_acc[r]);
    }
}

__global__ __launch_bounds__(256) void netvlad_epi(
    float* __restrict__ out, const float* __restrict__ asum_g,
    const float* __restrict__ cent) {
    __shared__ float wred[4];
    __shared__ float gs_sh;
    const int n = blockIdx.x;
    const int t = threadIdx.x;
    const int k = t >> 2;          // 4 threads per cluster row
    const int q = t & 3;
    float* op = out + (size_t)n * 16384 + k * 256 + q * 64;
    const float* cp = cent + k * 256 + q * 64;
    const float as = asum_g[n * 64 + k];

    float v[64];
    float ss = 0.f;
    #pragma unroll
    for (int i = 0; i < 64; i += 4) {
        const float4 av = *(const float4*)&op[i];
        const float4 cv = *(const float4*)&cp[i];
        v[i+0] = fmaf(-as, cv.x, av.x);
        v[i+1] = fmaf(-as, cv.y, av.y);
        v[i+2] = fmaf(-as, cv.z, av.z);
        v[i+3] = fmaf(-as, cv.w, av.w);
        ss = fmaf(v[i+0], v[i+0], ss);
        ss = fmaf(v[i+1], v[i+1], ss);
        ss = fmaf(v[i+2], v[i+2], ss);
        ss = fmaf(v[i+3], v[i+3], ss);
    }
    ss += __shfl_xor(ss, 1);
    ss += __shfl_xor(ss, 2);
    const float iscale = 1.f / fmaxf(sqrtf(ss), EPSF);

    float gsum = (q == 0) ? ss * iscale * iscale : 0.f;
    #pragma unroll
    for (int off = 4; off < 64; off <<= 1) gsum += __shfl_xor(gsum, off);
    if ((t & 63) == 0) wred[t >> 6] = gsum;
    __syncthreads();
    if (t == 0) {
        const float tot = wred[0] + wred[1] + wred[2] + wred[3];
        gs_sh = 1.f / fmaxf(sqrtf(tot), EPSF);
    }
    __syncthreads();
    const float fs = iscale * gs_sh;
    #pragma unroll
    for (int i = 0; i < 64; i += 4) {
        float4 w4;
        w4.x = v[i+0] * fs; w4.y = v[i+1] * fs;
        w4.z = v[i+2] * fs; w4.w = v[i+3] * fs;
        *(float4*)&op[i] = w4;
    }
}

extern "C" void kernel_launch(void* const* d_in, const int* in_sizes, int n_in,
                              void* d_out, int out_size, void* d_ws, size_t ws_size,
                              hipStream_t stream) {
    (void)in_sizes; (void)n_in; (void)ws_size;
    const float* x    = (const float*)d_in[0];
    const float* w    = (const float*)d_in[1];
    const float* b    = (const float*)d_in[2];
    const float* cent = (const float*)d_in[3];
    float* out    = (float*)d_out;
    float* asum_g = (float*)d_ws;          // 8192 floats

    hipMemsetAsync(d_out, 0, (size_t)out_size * sizeof(float), stream);
    hipMemsetAsync(asum_g, 0, 128 * 64 * sizeof(float), stream);
    netvlad_mfma<<<1024, 256, 0, stream>>>(x, w, b, out, asum_g);
    netvlad_epi<<<128, 256, 0, stream>>>(out, asum_g, cent);
}

// Round 7
// 106.430 us; speedup vs baseline: 2.4691x; 2.4691x over previous
//
#include <hip/hip_runtime.h>
#include <math.h>

// NetVLAD on MI355X via bf16 hi/lo-split MFMA (3-product emulated fp32).
// N=128 images, C=256 channels, K=64 clusters, P=1024 pixels.
// Block = (image, eighth): 128 pixels, 256 threads = 4 waves, 1024 blocks,
// 2 blocks/CU (LDS 71.4KB). R4 schedule (dbuf slabs, 1 barrier/slab,
// deferred write) + b128-aligned LDS layouts in BOTH passes.
// Pass 1 (contraction over c): slab [128 p][32 c] stride 36 -> b128 frags.
// Pass 2 (contraction over p): slab [32 c][128 p] stride 132 -> b128 frags,
//   aliased into buf (dead after A-frags registered). Coalesced atomics.
// MFMA 16x16x32 bf16: A row=l15,k=8*lg4+j; B col=l15,same k;
//                     C col=l15,row=4*lg4+reg  (verified R2-R5)

#define EPSF 1e-12f
#define XS1_LD 36      // u32 stride, pass-1 slab [128 p][32 c + pad]
#define XS2_LD 132     // u32 stride, pass-2 slab [32 c][128 p + pad]
#define BUF_LD 132     // u32/f32 stride, logits/a buffer [64 k][128 p + 4 pad]

typedef __attribute__((ext_vector_type(8))) __bf16 bf16x8;
typedef __attribute__((ext_vector_type(4))) float f32x4;
typedef __attribute__((ext_vector_type(4))) unsigned int u32x4;

#define MFMA(a, b, c) __builtin_amdgcn_mfma_f32_16x16x32_bf16((a), (b), (c), 0, 0, 0)

__device__ __forceinline__ bf16x8 as_bf(u32x4 v) { return __builtin_bit_cast(bf16x8, v); }

// f32 -> packed (hi_bf16 << 16) | lo_bf16  (truncation split, err ~2^-16|x|)
__device__ __forceinline__ unsigned packsplit(float x) {
    const unsigned u  = __float_as_uint(x);
    const unsigned hi = u & 0xFFFF0000u;
    const float lof   = x - __uint_as_float(hi);
    return hi | (__float_as_uint(lof) >> 16);
}

// 8 packed u32 (two aligned quads) -> (hi,lo) MFMA operand pair
__device__ __forceinline__ void unpack2q(const u32x4 q0, const u32x4 q1,
                                         u32x4& hi, u32x4& lo) {
    hi[0] = __builtin_amdgcn_perm(q0[1], q0[0], 0x07060302u);
    lo[0] = __builtin_amdgcn_perm(q0[1], q0[0], 0x05040100u);
    hi[1] = __builtin_amdgcn_perm(q0[3], q0[2], 0x07060302u);
    lo[1] = __builtin_amdgcn_perm(q0[3], q0[2], 0x05040100u);
    hi[2] = __builtin_amdgcn_perm(q1[1], q1[0], 0x07060302u);
    lo[2] = __builtin_amdgcn_perm(q1[1], q1[0], 0x05040100u);
    hi[3] = __builtin_amdgcn_perm(q1[3], q1[2], 0x07060302u);
    lo[3] = __builtin_amdgcn_perm(q1[3], q1[2], 0x05040100u);
}

__device__ __forceinline__ void split8v(const float* xv, u32x4& hi, u32x4& lo) {
    unsigned uh[8], ul[8];
    #pragma unroll
    for (int j = 0; j < 8; ++j) {
        const unsigned u = __float_as_uint(xv[j]);
        uh[j] = u;
        const float hif = __uint_as_float(u & 0xFFFF0000u);
        ul[j] = __float_as_uint(xv[j] - hif);
    }
    #pragma unroll
    for (int w2 = 0; w2 < 4; ++w2) {
        hi[w2] = (uh[2*w2+1] & 0xFFFF0000u) | (uh[2*w2] >> 16);
        lo[w2] = (ul[2*w2+1] & 0xFFFF0000u) | (ul[2*w2] >> 16);
    }
}

__global__ __launch_bounds__(256, 2) void netvlad_mfma(
    const float* __restrict__ x, const float* __restrict__ wmat,
    const float* __restrict__ bias, float* __restrict__ out,
    float* __restrict__ asum_g) {

    __shared__ __align__(16) unsigned xs1[2][128 * XS1_LD];  // pass-1 slab dbuf
    __shared__ __align__(16) unsigned buf[64 * BUF_LD];      // logits->a; pass-2 slab dbuf
    __shared__ __align__(16) float rn_lds[128];
    __shared__ float bias_lds[64];
    float* buf_f = (float*)buf;

    const int t = threadIdx.x;
    const int w = t >> 6, l = t & 63;
    const int l15 = l & 15, lg4 = l >> 4;
    const int n = blockIdx.x >> 3, e = blockIdx.x & 7;
    const size_t ximg = (size_t)n * 256 * 1024;
    const int p0 = e * 128;
    const int k0 = w * 16;                 // wave's 16-cluster tile
    const int cs = lg4 * 8;                // contraction slice base in K-step

    if (t < 64) bias_lds[t] = bias[t];

    // ---- W fragments (GEMM1 A), resident through pass 1: 64 VGPRs
    u32x4 whi[8], wlo[8];
    {
        const float* wr = wmat + (k0 + l15) * 256 + cs;
        #pragma unroll
        for (int s = 0; s < 8; ++s) {
            float xv[8];
            const float4 f0 = *(const float4*)(wr + s * 32);
            const float4 f1 = *(const float4*)(wr + s * 32 + 4);
            xv[0]=f0.x; xv[1]=f0.y; xv[2]=f0.z; xv[3]=f0.w;
            xv[4]=f1.x; xv[5]=f1.y; xv[6]=f1.z; xv[7]=f1.w;
            split8v(xv, whi[s], wlo[s]);
        }
    }

    // ---- pass-1 staging: thread owns (pixel pp, 16-channel half) per slab
    const int pp = t & 127, half = t >> 7;
    const float* xg1 = x + ximg + (size_t)(half * 16) * 1024 + p0 + pp;
    unsigned* const xw1base = (unsigned*)xs1 + pp * XS1_LD + half * 16;
    float g[16];
    float ssacc = 0.f;

    #define P1_LOAD(s_) { _Pragma("unroll")                                   \
        for (int i = 0; i < 16; ++i)                                          \
            g[i] = xg1[(size_t)((s_) * 32 + i) * 1024]; }
    #define P1_WRITE(b_) { unsigned* xw1 = xw1base + (b_) * 128 * XS1_LD;     \
        _Pragma("unroll")                                                     \
        for (int q = 0; q < 4; ++q) {                                         \
            u32x4 v;                                                          \
            _Pragma("unroll")                                                 \
            for (int j = 0; j < 4; ++j) {                                     \
                const float gv = g[q * 4 + j];                                \
                ssacc = fmaf(gv, gv, ssacc);                                  \
                v[j] = packsplit(gv);                                         \
            }                                                                 \
            *(u32x4*)(xw1 + q * 4) = v; } }

    // ================= PASS 1: logits + ss =================
    f32x4 acc1[8];
    #pragma unroll
    for (int i = 0; i < 8; ++i) acc1[i] = f32x4{0.f, 0.f, 0.f, 0.f};

    P1_LOAD(0);
    P1_WRITE(0);
    #pragma unroll
    for (int s = 0; s < 8; ++s) {
        if (s < 7) P1_LOAD(s + 1);
        __syncthreads();                       // slab s visible; dbuf safe
        const unsigned* sb = xs1[s & 1];
        #pragma unroll
        for (int nt = 0; nt < 8; ++nt) {
            const unsigned* rp = sb + (nt * 16 + l15) * XS1_LD + cs;
            const u32x4 q0 = *(const u32x4*)rp;
            const u32x4 q1 = *(const u32x4*)(rp + 4);
            u32x4 bhi, blo; unpack2q(q0, q1, bhi, blo);
            acc1[nt] = MFMA(as_bf(whi[s]), as_bf(bhi), acc1[nt]);
            acc1[nt] = MFMA(as_bf(whi[s]), as_bf(blo), acc1[nt]);
            acc1[nt] = MFMA(as_bf(wlo[s]), as_bf(bhi), acc1[nt]);
        }
        if (s < 7) P1_WRITE((s + 1) & 1);
    }

    // write raw logits + ss partials to buf (pad cols 128..131 hold sspart)
    #pragma unroll
    for (int nt = 0; nt < 8; ++nt) {
        #pragma unroll
        for (int r = 0; r < 4; ++r)
            buf_f[(k0 + lg4 * 4 + r) * BUF_LD + nt * 16 + l15] = acc1[nt][r];
    }
    buf_f[(t >> 2) * BUF_LD + 128 + (t & 3)] = ssacc;

    // ---- pass-2 staging ids; issue slab-0 loads early (hide under softmax)
    const int c2 = t >> 3, pq = (t & 7) * 4;
    const float* xg2 = x + ximg + (size_t)c2 * 1024 + p0 + pq;
    unsigned* const xw2base = buf + c2 * XS2_LD + pq;
    float4 g2[4];
    #define P2_LOAD(s_) { _Pragma("unroll")                                   \
        for (int i = 0; i < 4; ++i)                                           \
            g2[i] = *(const float4*)(xg2 + (size_t)(s_) * 32768 + 32 * i); }
    #define P2_WRITE(b_) { unsigned* xw2 = xw2base + (b_) * 32 * XS2_LD;      \
        _Pragma("unroll")                                                     \
        for (int i = 0; i < 4; ++i) {                                         \
            u32x4 v;                                                          \
            v[0] = packsplit(g2[i].x); v[1] = packsplit(g2[i].y);             \
            v[2] = packsplit(g2[i].z); v[3] = packsplit(g2[i].w);             \
            *(u32x4*)(xw2 + 32 * i) = v; } }
    P2_LOAD(0);
    __syncthreads();                           // logits + sspart visible

    // ---- softmax: one pixel per thread (t<128); rn folded here
    if (t < 128) {
        const float ssv = buf_f[(t >> 2) * BUF_LD + 128 + (t & 3)]
                        + buf_f[((t >> 2) + 32) * BUF_LD + 128 + (t & 3)];
        const float rn = 1.f / fmaxf(sqrtf(ssv), EPSF);
        rn_lds[t] = rn;
        float a[64];
        #pragma unroll
        for (int k = 0; k < 64; ++k)
            a[k] = fmaf(buf_f[k * BUF_LD + t], rn, bias_lds[k]);
        float mx = -3.402823466e38f;
        #pragma unroll
        for (int k = 0; k < 64; ++k) mx = fmaxf(mx, a[k]);
        float den = 0.f;
        #pragma unroll
        for (int k = 0; k < 64; ++k) { a[k] = __expf(a[k] - mx); den += a[k]; }
        const float inv = 1.f / den;
        #pragma unroll
        for (int k = 0; k < 64; ++k)
            buf[k * BUF_LD + t] = packsplit(a[k] * inv);   // raw a, packed split
    }
    __syncthreads();                           // packed a visible

    // ---- A-frags for pass 2: raw a (asum) + a*rn resplit; held for all slabs
    u32x4 aphi[4], aplo[4];
    f32x4 asum_acc = f32x4{0.f, 0.f, 0.f, 0.f};
    const u32x4 ONES = {0x3F803F80u, 0x3F803F80u, 0x3F803F80u, 0x3F803F80u};
    #pragma unroll
    for (int ks = 0; ks < 4; ++ks) {
        const unsigned* ap = buf + (k0 + l15) * BUF_LD + ks * 32 + cs;
        const u32x4 pa = *(const u32x4*)ap;
        const u32x4 pb = *(const u32x4*)(ap + 4);
        u32x4 ahi, alo; unpack2q(pa, pb, ahi, alo);
        asum_acc = MFMA(as_bf(ahi), as_bf(ONES), asum_acc);
        asum_acc = MFMA(as_bf(alo), as_bf(ONES), asum_acc);
        // a' = a*rn, resplit once; reused by all 16 c-tiles
        const float* rp = rn_lds + ks * 32 + cs;
        const unsigned paw[8] = {pa[0],pa[1],pa[2],pa[3],pb[0],pb[1],pb[2],pb[3]};
        float av[8];
        #pragma unroll
        for (int j = 0; j < 8; ++j) {
            const float afv = __uint_as_float(paw[j] & 0xFFFF0000u)
                            + __uint_as_float(paw[j] << 16);
            av[j] = afv * rp[j];
        }
        split8v(av, aphi[ks], aplo[ks]);
    }
    __syncthreads();                           // buf reads done -> region free

    P2_WRITE(0);                               // slab 0 into buf rows 0..31

    // ================= PASS 2: agg[k][c] += a' @ x^T =================
    float* op = out + (size_t)n * 16384;
    #pragma unroll
    for (int s2 = 0; s2 < 8; ++s2) {
        if (s2 < 7) P2_LOAD(s2 + 1);
        __syncthreads();                       // slab s2 visible; dbuf safe
        const unsigned* sb = buf + (s2 & 1) * 32 * XS2_LD;
        #pragma unroll
        for (int ntl = 0; ntl < 2; ++ntl) {
            f32x4 a2 = f32x4{0.f, 0.f, 0.f, 0.f};
            #pragma unroll
            for (int ks = 0; ks < 4; ++ks) {
                const unsigned* rp = sb + (ntl * 16 + l15) * XS2_LD + ks * 32 + cs;
                const u32x4 q0 = *(const u32x4*)rp;
                const u32x4 q1 = *(const u32x4*)(rp + 4);
                u32x4 xhi, xlo; unpack2q(q0, q1, xhi, xlo);
                a2 = MFMA(as_bf(aphi[ks]), as_bf(xhi), a2);
                a2 = MFMA(as_bf(aphi[ks]), as_bf(xlo), a2);
                a2 = MFMA(as_bf(aplo[ks]), as_bf(xhi), a2);
            }
            // C: col=l15 -> channel (coalesced per 16 lanes), row -> cluster
            const int c = s2 * 32 + ntl * 16 + l15;
            #pragma unroll
            for (int r = 0; r < 4; ++r)
                atomicAdd(&op[(k0 + lg4 * 4 + r) * 256 + c], a2[r]);
        }
        if (s2 < 7) P2_WRITE((s2 + 1) & 1);
    }
    if (l15 == 0) {
        #pragma unroll
        for (int r = 0; r < 4; ++r)
            atomicAdd(&asum_g[n * 64 + k0 + lg4 * 4 + r], asum_acc[r]);
    }
}

__global__ __launch_bounds__(256) void netvlad_epi(
    float* __restrict__ out, const float* __restrict__ asum_g,
    const float* __restrict__ cent) {
    __shared__ float wred[4];
    __shared__ float gs_sh;
    const int n = blockIdx.x;
    const int t = threadIdx.x;
    const int k = t >> 2;          // 4 threads per cluster row
    const int q = t & 3;
    float* op = out + (size_t)n * 16384 + k * 256 + q * 64;
    const float* cp = cent + k * 256 + q * 64;
    const float as = asum_g[n * 64 + k];

    float v[64];
    float ss = 0.f;
    #pragma unroll
    for (int i = 0; i < 64; i += 4) {
        const float4 av = *(const float4*)&op[i];
        const float4 cv = *(const float4*)&cp[i];
        v[i+0] = fmaf(-as, cv.x, av.x);
        v[i+1] = fmaf(-as, cv.y, av.y);
        v[i+2] = fmaf(-as, cv.z, av.z);
        v[i+3] = fmaf(-as, cv.w, av.w);
        ss = fmaf(v[i+0], v[i+0], ss);
        ss = fmaf(v[i+1], v[i+1], ss);
        ss = fmaf(v[i+2], v[i+2], ss);
        ss = fmaf(v[i+3], v[i+3], ss);
    }
    ss += __shfl_xor(ss, 1);
    ss += __shfl_xor(ss, 2);
    const float iscale = 1.f / fmaxf(sqrtf(ss), EPSF);

    float gsum = (q == 0) ? ss * iscale * iscale : 0.f;
    #pragma unroll
    for (int off = 4; off < 64; off <<= 1) gsum += __shfl_xor(gsum, off);
    if ((t & 63) == 0) wred[t >> 6] = gsum;
    __syncthreads();
    if (t == 0) {
        const float tot = wred[0] + wred[1] + wred[2] + wred[3];
        gs_sh = 1.f / fmaxf(sqrtf(tot), EPSF);
    }
    __syncthreads();
    const float fs = iscale * gs_sh;
    #pragma unroll
    for (int i = 0; i < 64; i += 4) {
        float4 w4;
        w4.x = v[i+0] * fs; w4.y = v[i+1] * fs;
        w4.z = v[i+2] * fs; w4.w = v[i+3] * fs;
        *(float4*)&op[i] = w4;
    }
}

extern "C" void kernel_launch(void* const* d_in, const int* in_sizes, int n_in,
                              void* d_out, int out_size, void* d_ws, size_t ws_size,
                              hipStream_t stream) {
    (void)in_sizes; (void)n_in; (void)ws_size;
    const float* x    = (const float*)d_in[0];
    const float* w    = (const float*)d_in[1];
    const float* b    = (const float*)d_in[2];
    const float* cent = (const float*)d_in[3];
    float* out    = (float*)d_out;
    float* asum_g = (float*)d_ws;          // 8192 floats

    hipMemsetAsync(d_out, 0, (size_t)out_size * sizeof(float), stream);
    hipMemsetAsync(asum_g, 0, 128 * 64 * sizeof(float), stream);
    netvlad_mfma<<<1024, 256, 0, stream>>>(x, w, b, out, asum_g);
    netvlad_epi<<<128, 256, 0, stream>>>(out, asum_g, cent);
}